// Round 4
// baseline (183.825 us; speedup 1.0000x reference)
//
#include <hip/hip_runtime.h>
#include <math.h>

#define NN 4096
#define DD 128
#define BM 32           // gemm rows per block
#define ALPHA_C 16.0f
#define KSEL 32         // threshold = (K+1)-th smallest, 0-based index K

// ---- float <-> order-preserving u32 key ----
__device__ __forceinline__ unsigned f2k(float f) {
  unsigned b = __float_as_uint(f);
  return (b & 0x80000000u) ? ~b : (b | 0x80000000u);
}
__device__ __forceinline__ float k2f(unsigned k) {
  unsigned b = (k & 0x80000000u) ? (k & 0x7FFFFFFFu) : ~k;
  return __uint_as_float(b);
}

// ---- wave (64-lane) butterfly reductions ----
__device__ __forceinline__ double wsum_d(double v) {
  #pragma unroll
  for (int m = 32; m; m >>= 1) v += __shfl_xor(v, m, 64);
  return v;
}
__device__ __forceinline__ int wsum_i(int v) {
  #pragma unroll
  for (int m = 32; m; m >>= 1) v += __shfl_xor(v, m, 64);
  return v;
}
__device__ __forceinline__ float wmin_f(float v) {
  #pragma unroll
  for (int m = 32; m; m >>= 1) v = fminf(v, __shfl_xor(v, m, 64));
  return v;
}

// ---- kernel 1: transpose x[N][D] -> xT[D][N] ----
__global__ void nca_transpose(const float* __restrict__ x, float* __restrict__ xT) {
  int idx = blockIdx.x * blockDim.x + threadIdx.x;
  int stride = gridDim.x * blockDim.x;
  for (int i = idx; i < NN * DD; i += stride) {
    int n = i >> 7;
    int d = i & (DD - 1);
    xT[d * NN + n] = x[i];
  }
}

// ---- kernel 2: GEMM -> keys. Block: BM=32 rows x 1024 cols, 256 threads ----
__global__ __launch_bounds__(256) void nca_gemm(
    const float* __restrict__ x, const float* __restrict__ xT,
    unsigned* __restrict__ keys, int row0) {
  __shared__ float4 xi4[BM][DD / 4];   // 16 KB

  const int tid = threadIdx.x;
  const int rg  = blockIdx.x >> 2;
  const int cg  = blockIdx.x & 3;
  const int r0g = row0 + rg * BM;      // first global row of this block
  const int j0  = (cg << 10) + (tid << 2);

  for (int k = tid; k < BM * DD / 4; k += 256)
    reinterpret_cast<float4*>(xi4)[k] =
        reinterpret_cast<const float4*>(x + (size_t)r0g * DD)[k];
  __syncthreads();

  float acc[BM][4];
  #pragma unroll
  for (int r = 0; r < BM; ++r)
    #pragma unroll
    for (int q = 0; q < 4; ++q) acc[r][q] = 0.0f;

  #pragma unroll 2
  for (int d = 0; d < DD; d += 4) {
    float4 b0 = *reinterpret_cast<const float4*>(xT + (size_t)(d + 0) * NN + j0);
    float4 b1 = *reinterpret_cast<const float4*>(xT + (size_t)(d + 1) * NN + j0);
    float4 b2 = *reinterpret_cast<const float4*>(xT + (size_t)(d + 2) * NN + j0);
    float4 b3 = *reinterpret_cast<const float4*>(xT + (size_t)(d + 3) * NN + j0);
    float bb[4][4] = {{b0.x, b0.y, b0.z, b0.w}, {b1.x, b1.y, b1.z, b1.w},
                      {b2.x, b2.y, b2.z, b2.w}, {b3.x, b3.y, b3.z, b3.w}};
    const int dq = d >> 2;
    #pragma unroll
    for (int r = 0; r < BM; ++r) {
      float4 a = xi4[r][dq];
      float aa[4] = {a.x, a.y, a.z, a.w};
      #pragma unroll
      for (int dd = 0; dd < 4; ++dd)
        #pragma unroll
        for (int q = 0; q < 4; ++q)
          acc[r][q] = fmaf(aa[dd], bb[dd][q], acc[r][q]);
    }
  }

  // store keys (order-preserving u32), coalesced uint4
  #pragma unroll
  for (int r = 0; r < BM; ++r) {
    uint4 kk;
    kk.x = f2k(acc[r][0]); kk.y = f2k(acc[r][1]);
    kk.z = f2k(acc[r][2]); kk.w = f2k(acc[r][3]);
    *reinterpret_cast<uint4*>(keys + (size_t)(r0g - row0 + r) * NN + j0) = kk;
  }
}

// ---- kernel 3: per-row select + sums. 1 wave = 1 row, 4 waves/block ----
__global__ __launch_bounds__(256, 4) void nca_select(
    const float* __restrict__ x, const unsigned* __restrict__ keys,
    const int* __restrict__ tgt, float* __restrict__ row_loss,
    float* __restrict__ out, int row0) {
  __shared__ unsigned cbuf[4][64];     // 1 KB: candidate compaction

  const int tid  = threadIdx.x;
  const int w    = tid >> 6;
  const int lane = tid & 63;
  const int i    = row0 + blockIdx.x * 4 + w;
  const int ti   = tgt[i];
  const int lb   = lane << 2;
  const unsigned* krow = keys + (size_t)(i - row0) * NN;

  // f64 self-dot (decision sim[i][i] < 1.0 must match f64-accurate reference)
  double sx0 = (double)x[i * DD + lane], sx1 = (double)x[i * DD + lane + 64];
  const double selfd = wsum_d(sx0 * sx0 + sx1 * sx1);
  const bool self_pos = (selfd < 1.0);

  // load keys; base = row mean of decoded sims (f64 sum, BEFORE self exclusion)
  unsigned kv[64];
  double bs = 0.0;
  #pragma unroll
  for (int kk = 0; kk < 16; ++kk) {
    uint4 k4 = *reinterpret_cast<const uint4*>(krow + (kk << 8) + lb);
    kv[kk * 4 + 0] = k4.x; kv[kk * 4 + 1] = k4.y;
    kv[kk * 4 + 2] = k4.z; kv[kk * 4 + 3] = k4.w;
    bs += (double)k2f(k4.x) + (double)k2f(k4.y) +
          (double)k2f(k4.z) + (double)k2f(k4.w);
  }
  const float basef = (float)(wsum_d(bs) * (1.0 / NN));

  // exclude self (sim>=1): set its key to max (decodes to NaN in pass 2)
  if (!self_pos) {
    #pragma unroll
    for (int kk = 0; kk < 16; ++kk)
      #pragma unroll
      for (int q = 0; q < 4; ++q)
        if (((kk << 8) + lb + q) == i) kv[kk * 4 + q] = 0xFFFFFFFFu;
  }

  // ---- exact rank-KSEL select: heavy bitwise rounds until window <= 64 ----
  unsigned lo = 0;
  int nLo = 0, nHi = NN, b = 31;
  while (b >= 0 && (nHi - nLo) > 64) {
    unsigned mid = lo | (1u << b);
    int c = 0;
    #pragma unroll
    for (int t = 0; t < 64; ++t) c += (kv[t] < mid) ? 1 : 0;
    c = wsum_i(c);
    if (c <= KSEL) { lo = mid; nLo = c; }
    else nHi = c;
    --b;
  }

  unsigned keysel;
  if ((nHi - nLo) <= 64) {
    // compact window candidates (prefix == lo >> shift) one-per-lane
    const int shift = b + 1;                   // 0..31 (b can be -1)
    const unsigned pfx = (shift >= 32) ? 0u : (lo >> shift);
    int cnt = 0;
    #pragma unroll
    for (int t = 0; t < 64; ++t) cnt += ((kv[t] >> shift) == pfx) ? 1 : 0;
    int incl = cnt;
    #pragma unroll
    for (int off = 1; off < 64; off <<= 1) {
      int o = __shfl_up(incl, off, 64);
      if (lane >= off) incl += o;
    }
    const int total = __shfl(incl, 63, 64);
    int idx = incl - cnt;
    #pragma unroll
    for (int t = 0; t < 64; ++t)
      if ((kv[t] >> shift) == pfx) cbuf[w][idx++] = kv[t];
    unsigned v = cbuf[w][lane];                // garbage if lane >= total (masked)

    unsigned long long amask =
        (total >= 64) ? ~0ull : ((1ull << total) - 1ull);
    int ww = KSEL - nLo;                       // 0-based rank within window
    for (int bb = b; bb >= 0; --bb) {
      unsigned long long z = __ballot(((amask >> lane) & 1ull) &&
                                      (((v >> bb) & 1u) == 0u));
      int zc = __popcll(z);
      if (ww < zc) amask = z;
      else { ww -= zc; amask &= ~z; }
    }
    int first = __ffsll((unsigned long long)amask) - 1;
    keysel = __shfl(v, first, 64);
  } else {
    keysel = lo;  // bits exhausted with >64 exact ties: key fully resolved
  }
  const float thr = k2f(keysel);

  // ---- pass 2: weighted sums below threshold, min positive, has-pos ----
  double psum = 0.0, nsum = 0.0;
  float minp = __builtin_inff();
  int hasp = 0;
  #pragma unroll
  for (int kk = 0; kk < 16; ++kk) {
    int4 t4 = *reinterpret_cast<const int4*>(tgt + (kk << 8) + lb);
    int tj[4] = {t4.x, t4.y, t4.z, t4.w};
    #pragma unroll
    for (int q = 0; q < 4; ++q) {
      int t = kk * 4 + q;
      int j = (kk << 8) + lb + q;
      float s = k2f(kv[t]);    // NaN for excluded self -> all predicates false
      bool same = (tj[q] == ti);
      bool vpos = same && ((j == i) ? self_pos : (s < 1.0f));
      if (vpos) minp = fminf(minp, s);
      if (s < thr) {
        float wgt = expf(ALPHA_C * (basef - s));
        if (vpos) { psum += (double)wgt; hasp = 1; }
        else if (!same) nsum += (double)wgt;
      }
    }
  }
  double tpsum = wsum_d(psum);
  double tnsum = wsum_d(nsum);
  float  tminp = wmin_f(minp);
  int    thasp = wsum_i(hasp);

  // diagnostics from the last row only (wave-uniform branch)
  if (i == NN - 1) {
    double pss = 0.0, nss = 0.0;
    int pct = 0, nct = 0;
    #pragma unroll
    for (int kk = 0; kk < 16; ++kk) {
      int4 t4 = *reinterpret_cast<const int4*>(tgt + (kk << 8) + lb);
      int tj[4] = {t4.x, t4.y, t4.z, t4.w};
      #pragma unroll
      for (int q = 0; q < 4; ++q) {
        int t = kk * 4 + q;
        int j = (kk << 8) + lb + q;
        float s = k2f(kv[t]);
        bool same = (tj[q] == ti);
        bool vpos = same && ((j == i) ? self_pos : (s < 1.0f));
        if (vpos) { pss += (double)s; pct++; }
        if (!same) { nss += (double)s; nct++; }
      }
    }
    pss = wsum_d(pss); nss = wsum_d(nss);
    pct = wsum_i(pct); nct = wsum_i(nct);
    if (lane == 0) {
      out[2] = (float)(pss / (double)pct);
      out[3] = (float)(nss / (double)nct);
    }
  }

  if (lane == 0) {
    float pl = (thasp > 0) ? (float)tpsum
                           : expf(ALPHA_C * (basef - tminp));
    row_loss[i] = -logf(pl / (pl + (float)tnsum));
  }
}

// ---- kernel 4: deterministic mean of per-row losses ----
__global__ void nca_final(const float* __restrict__ row_loss, float* __restrict__ out) {
  __shared__ double redd[4];
  int tid = threadIdx.x;
  double s = 0.0;
  for (int i = tid; i < NN; i += 256) s += (double)row_loss[i];
  #pragma unroll
  for (int m = 32; m; m >>= 1) s += __shfl_xor(s, m, 64);
  if ((tid & 63) == 0) redd[tid >> 6] = s;
  __syncthreads();
  if (tid == 0) {
    double tot = redd[0] + redd[1] + redd[2] + redd[3];
    out[0] = (float)(tot * (1.0 / NN));
    out[1] = 0.0f;
  }
}

extern "C" void kernel_launch(void* const* d_in, const int* in_sizes, int n_in,
                              void* d_out, int out_size, void* d_ws, size_t ws_size,
                              hipStream_t stream) {
  const float* x  = (const float*)d_in[0];
  const int* tgt  = (const int*)d_in[1];
  float* out      = (float*)d_out;

  float* xT        = (float*)d_ws;                       // 2 MB
  float* row_loss  = xT + (size_t)NN * DD;               // 16 KB
  unsigned* keys   = (unsigned*)(row_loss + NN);
  size_t used      = ((size_t)NN * DD + NN) * sizeof(float);
  size_t cap_rows  = (ws_size > used) ? (ws_size - used) / ((size_t)NN * 4) : 0;
  int chunk = (int)((cap_rows / BM) * BM);
  if (chunk <= 0) chunk = BM;          // last resort (ws assumed >= ~2.6 MB)
  if (chunk > NN) chunk = NN;

  nca_transpose<<<512, 256, 0, stream>>>(x, xT);
  for (int r0 = 0; r0 < NN; r0 += chunk) {
    int rows = (NN - r0 < chunk) ? (NN - r0) : chunk;
    nca_gemm<<<(rows / BM) * 4, 256, 0, stream>>>(x, xT, keys, r0);
    nca_select<<<rows / 4, 256, 0, stream>>>(x, keys, tgt, row_loss, out, r0);
  }
  nca_final<<<1, 256, 0, stream>>>(row_loss, out);
}

// Round 5
// 111.652 us; speedup vs baseline: 1.6464x; 1.6464x over previous
//
#include <hip/hip_runtime.h>
#include <math.h>

#define NN 4096
#define DD 128
#define ALPHA_C 16.0f
#define KSEL 32         // threshold = (K+1)-th smallest, 0-based index K

typedef __attribute__((ext_vector_type(8))) short bf16x8;
typedef __attribute__((ext_vector_type(4))) float f32x4;

// ---- float <-> order-preserving u32 key ----
__device__ __forceinline__ unsigned f2k(float f) {
  unsigned b = __float_as_uint(f);
  return (b & 0x80000000u) ? ~b : (b | 0x80000000u);
}
__device__ __forceinline__ float k2f(unsigned k) {
  unsigned b = (k & 0x80000000u) ? (k & 0x7FFFFFFFu) : ~k;
  return __uint_as_float(b);
}

// ---- wave (64-lane) butterfly reductions ----
__device__ __forceinline__ double wsum_d(double v) {
  #pragma unroll
  for (int m = 32; m; m >>= 1) v += __shfl_xor(v, m, 64);
  return v;
}
__device__ __forceinline__ int wsum_i(int v) {
  #pragma unroll
  for (int m = 32; m; m >>= 1) v += __shfl_xor(v, m, 64);
  return v;
}
__device__ __forceinline__ float wmin_f(float v) {
  #pragma unroll
  for (int m = 32; m; m >>= 1) v = fminf(v, __shfl_xor(v, m, 64));
  return v;
}

// ---- kernel 1: split x (f32) -> bf16 hi + bf16 lo (RNE both) ----
__global__ __launch_bounds__(256) void nca_prep(
    const float* __restrict__ x, short* __restrict__ xhi, short* __restrict__ xlo) {
  int idx = blockIdx.x * blockDim.x + threadIdx.x;   // 0 .. N*D/4-1
  float4 v = reinterpret_cast<const float4*>(x)[idx];
  float vv[4] = {v.x, v.y, v.z, v.w};
  short h[4], l[4];
  #pragma unroll
  for (int q = 0; q < 4; ++q) {
    unsigned u  = __float_as_uint(vv[q]);
    unsigned hb = (u + 0x7FFFu + ((u >> 16) & 1u)) >> 16;
    float hf    = __uint_as_float(hb << 16);
    float lf    = vv[q] - hf;
    unsigned ul = __float_as_uint(lf);
    unsigned lb = (ul + 0x7FFFu + ((ul >> 16) & 1u)) >> 16;
    h[q] = (short)hb; l[q] = (short)lb;
  }
  reinterpret_cast<short4*>(xhi)[idx] = make_short4(h[0], h[1], h[2], h[3]);
  reinterpret_cast<short4*>(xlo)[idx] = make_short4(l[0], l[1], l[2], l[3]);
}

// ---- kernel 2: MFMA GEMM sim = X X^T (bf16x3) -> u32 keys ----
// block: 32 rows x 256 cols, 4 waves; wave: 32 rows x 64 cols = 2x4 16x16 tiles
__global__ __launch_bounds__(256) void nca_gemm(
    const short* __restrict__ xhi, const short* __restrict__ xlo,
    unsigned* __restrict__ keys) {
  const int tid = threadIdx.x;
  const int w   = tid >> 6;
  const int l   = tid & 63;
  const int rg  = blockIdx.x >> 4;
  const int cg  = blockIdx.x & 15;
  const int R   = rg << 5;                 // 32 rows
  const int C   = (cg << 8) + (w << 6);    // 64 cols per wave
  const int lr  = l & 15;                  // row/col within tile
  const int lk  = (l >> 4) << 3;           // k-offset within 32-wide k-block

  f32x4 acc[2][4];
  #pragma unroll
  for (int rt = 0; rt < 2; ++rt)
    #pragma unroll
    for (int t = 0; t < 4; ++t) acc[rt][t] = (f32x4){0.f, 0.f, 0.f, 0.f};

  #pragma unroll
  for (int kb = 0; kb < 4; ++kb) {
    const int ko = (kb << 5) + lk;
    bf16x8 ah[2], al[2], bh[4], bl[4];
    #pragma unroll
    for (int rt = 0; rt < 2; ++rt) {
      const size_t off = (size_t)(R + (rt << 4) + lr) * DD + ko;
      ah[rt] = *reinterpret_cast<const bf16x8*>(xhi + off);
      al[rt] = *reinterpret_cast<const bf16x8*>(xlo + off);
    }
    #pragma unroll
    for (int t = 0; t < 4; ++t) {
      const size_t off = (size_t)(C + (t << 4) + lr) * DD + ko;
      bh[t] = *reinterpret_cast<const bf16x8*>(xhi + off);
      bl[t] = *reinterpret_cast<const bf16x8*>(xlo + off);
    }
    #pragma unroll
    for (int rt = 0; rt < 2; ++rt)
      #pragma unroll
      for (int t = 0; t < 4; ++t) {
        acc[rt][t] = __builtin_amdgcn_mfma_f32_16x16x32_bf16(ah[rt], bh[t], acc[rt][t], 0, 0, 0);
        acc[rt][t] = __builtin_amdgcn_mfma_f32_16x16x32_bf16(ah[rt], bl[t], acc[rt][t], 0, 0, 0);
        acc[rt][t] = __builtin_amdgcn_mfma_f32_16x16x32_bf16(al[rt], bh[t], acc[rt][t], 0, 0, 0);
      }
  }

  // C/D layout (m89-verified): col = lane&15, row = (lane>>4)*4 + reg
  const int rbase = (l >> 4) << 2;
  const int cc    = l & 15;
  #pragma unroll
  for (int rt = 0; rt < 2; ++rt)
    #pragma unroll
    for (int t = 0; t < 4; ++t)
      #pragma unroll
      for (int r = 0; r < 4; ++r)
        keys[(size_t)(R + (rt << 4) + rbase + r) * NN + C + (t << 4) + cc] =
            f2k(acc[rt][t][r]);
}

// ---- kernel 3: per-row select + sums. 1 wave = 1 row, 4 waves/block ----
__global__ __launch_bounds__(256, 4) void nca_select(
    const float* __restrict__ x, const unsigned* __restrict__ keys,
    const int* __restrict__ tgt, float* __restrict__ row_loss,
    float* __restrict__ out) {
  __shared__ unsigned cbuf[4][64];     // 1 KB: candidate compaction

  const int tid  = threadIdx.x;
  const int w    = tid >> 6;
  const int lane = tid & 63;
  const int i    = blockIdx.x * 4 + w;
  const int ti   = tgt[i];
  const int lb   = lane << 2;
  const unsigned* krow = keys + (size_t)i * NN;

  // f64 self-dot (decision sim[i][i] < 1.0 must match f64-accurate reference)
  double sx0 = (double)x[i * DD + lane], sx1 = (double)x[i * DD + lane + 64];
  const double selfd = wsum_d(sx0 * sx0 + sx1 * sx1);
  const bool self_pos = (selfd < 1.0);

  // load keys; base = row mean of decoded sims (f64 sum, BEFORE self exclusion)
  unsigned kv[64];
  double bs = 0.0;
  #pragma unroll
  for (int kk = 0; kk < 16; ++kk) {
    uint4 k4 = *reinterpret_cast<const uint4*>(krow + (kk << 8) + lb);
    kv[kk * 4 + 0] = k4.x; kv[kk * 4 + 1] = k4.y;
    kv[kk * 4 + 2] = k4.z; kv[kk * 4 + 3] = k4.w;
    bs += (double)k2f(k4.x) + (double)k2f(k4.y) +
          (double)k2f(k4.z) + (double)k2f(k4.w);
  }
  const float basef = (float)(wsum_d(bs) * (1.0 / NN));

  // exclude self (sim>=1): set its key to max (decodes to NaN in pass 2)
  if (!self_pos) {
    #pragma unroll
    for (int kk = 0; kk < 16; ++kk)
      #pragma unroll
      for (int q = 0; q < 4; ++q)
        if (((kk << 8) + lb + q) == i) kv[kk * 4 + q] = 0xFFFFFFFFu;
  }

  // ---- exact rank-KSEL select: heavy bitwise rounds until window <= 64 ----
  unsigned lo = 0;
  int nLo = 0, nHi = NN, b = 31;
  while (b >= 0 && (nHi - nLo) > 64) {
    unsigned mid = lo | (1u << b);
    int c = 0;
    #pragma unroll
    for (int t = 0; t < 64; ++t) c += (kv[t] < mid) ? 1 : 0;
    c = wsum_i(c);
    if (c <= KSEL) { lo = mid; nLo = c; }
    else nHi = c;
    --b;
  }

  unsigned keysel;
  if ((nHi - nLo) <= 64) {
    // compact window candidates (prefix == lo >> shift) one-per-lane
    const int shift = b + 1;                   // 0..31 (b can be -1)
    const unsigned pfx = (shift >= 32) ? 0u : (lo >> shift);
    int cnt = 0;
    #pragma unroll
    for (int t = 0; t < 64; ++t) cnt += ((kv[t] >> shift) == pfx) ? 1 : 0;
    int incl = cnt;
    #pragma unroll
    for (int off = 1; off < 64; off <<= 1) {
      int o = __shfl_up(incl, off, 64);
      if (lane >= off) incl += o;
    }
    const int total = __shfl(incl, 63, 64);
    int idx = incl - cnt;
    #pragma unroll
    for (int t = 0; t < 64; ++t)
      if ((kv[t] >> shift) == pfx) cbuf[w][idx++] = kv[t];
    unsigned v = cbuf[w][lane];                // garbage if lane >= total (masked)

    unsigned long long amask =
        (total >= 64) ? ~0ull : ((1ull << total) - 1ull);
    int ww = KSEL - nLo;                       // 0-based rank within window
    for (int bb = b; bb >= 0; --bb) {
      unsigned long long z = __ballot(((amask >> lane) & 1ull) &&
                                      (((v >> bb) & 1u) == 0u));
      int zc = __popcll(z);
      if (ww < zc) amask = z;
      else { ww -= zc; amask &= ~z; }
    }
    int first = __ffsll((unsigned long long)amask) - 1;
    keysel = __shfl(v, first, 64);
  } else {
    keysel = lo;  // bits exhausted with >64 exact ties: key fully resolved
  }
  const float thr = k2f(keysel);

  // ---- pass 2: weighted sums below threshold, min positive, has-pos ----
  double psum = 0.0, nsum = 0.0;
  float minp = __builtin_inff();
  int hasp = 0;
  #pragma unroll
  for (int kk = 0; kk < 16; ++kk) {
    int4 t4 = *reinterpret_cast<const int4*>(tgt + (kk << 8) + lb);
    int tj[4] = {t4.x, t4.y, t4.z, t4.w};
    #pragma unroll
    for (int q = 0; q < 4; ++q) {
      int t = kk * 4 + q;
      int j = (kk << 8) + lb + q;
      float s = k2f(kv[t]);    // NaN for excluded self -> all predicates false
      bool same = (tj[q] == ti);
      bool vpos = same && ((j == i) ? self_pos : (s < 1.0f));
      if (vpos) minp = fminf(minp, s);
      if (s < thr) {
        float wgt = expf(ALPHA_C * (basef - s));
        if (vpos) { psum += (double)wgt; hasp = 1; }
        else if (!same) nsum += (double)wgt;
      }
    }
  }
  double tpsum = wsum_d(psum);
  double tnsum = wsum_d(nsum);
  float  tminp = wmin_f(minp);
  int    thasp = wsum_i(hasp);

  // diagnostics from the last row only (wave-uniform branch)
  if (i == NN - 1) {
    double pss = 0.0, nss = 0.0;
    int pct = 0, nct = 0;
    #pragma unroll
    for (int kk = 0; kk < 16; ++kk) {
      int4 t4 = *reinterpret_cast<const int4*>(tgt + (kk << 8) + lb);
      int tj[4] = {t4.x, t4.y, t4.z, t4.w};
      #pragma unroll
      for (int q = 0; q < 4; ++q) {
        int t = kk * 4 + q;
        int j = (kk << 8) + lb + q;
        float s = k2f(kv[t]);
        bool same = (tj[q] == ti);
        bool vpos = same && ((j == i) ? self_pos : (s < 1.0f));
        if (vpos) { pss += (double)s; pct++; }
        if (!same) { nss += (double)s; nct++; }
      }
    }
    pss = wsum_d(pss); nss = wsum_d(nss);
    pct = wsum_i(pct); nct = wsum_i(nct);
    if (lane == 0) {
      out[2] = (float)(pss / (double)pct);
      out[3] = (float)(nss / (double)nct);
    }
  }

  if (lane == 0) {
    float pl = (thasp > 0) ? (float)tpsum
                           : expf(ALPHA_C * (basef - tminp));
    row_loss[i] = -logf(pl / (pl + (float)tnsum));
  }
}

// ---- kernel 4: deterministic mean of per-row losses ----
__global__ void nca_final(const float* __restrict__ row_loss, float* __restrict__ out) {
  __shared__ double redd[4];
  int tid = threadIdx.x;
  double s = 0.0;
  for (int i = tid; i < NN; i += 256) s += (double)row_loss[i];
  #pragma unroll
  for (int m = 32; m; m >>= 1) s += __shfl_xor(s, m, 64);
  if ((tid & 63) == 0) redd[tid >> 6] = s;
  __syncthreads();
  if (tid == 0) {
    double tot = redd[0] + redd[1] + redd[2] + redd[3];
    out[0] = (float)(tot * (1.0 / NN));
    out[1] = 0.0f;
  }
}

extern "C" void kernel_launch(void* const* d_in, const int* in_sizes, int n_in,
                              void* d_out, int out_size, void* d_ws, size_t ws_size,
                              hipStream_t stream) {
  const float* x  = (const float*)d_in[0];
  const int* tgt  = (const int*)d_in[1];
  float* out      = (float*)d_out;

  // ws layout: xhi (1 MB) | xlo (1 MB) | row_loss (16 KB) | keys (64 MB)
  short* xhi       = (short*)d_ws;
  short* xlo       = xhi + (size_t)NN * DD;
  float* row_loss  = (float*)(xlo + (size_t)NN * DD);
  unsigned* keys   = (unsigned*)(row_loss + NN);

  nca_prep<<<(NN * DD / 4) / 256, 256, 0, stream>>>(x, xhi, xlo);
  nca_gemm<<<(NN / 32) * (NN / 256), 256, 0, stream>>>(xhi, xlo, keys);
  nca_select<<<NN / 4, 256, 0, stream>>>(x, keys, tgt, row_loss, out);
  nca_final<<<1, 256, 0, stream>>>(row_loss, out);
}